// Round 19
// baseline (436.510 us; speedup 1.0000x reference)
//
#include <hip/hip_runtime.h>

#define N_NODES 20000
#define N_PAD 20096            // 157 * 128
#define N_EDGES 320000
#define HIDDEN 256
#define N_GRAPHS 64
#define OUT_DIM 2

#define QPANEL_BYTES 65536     // one col-quarter (64 cols): hi(32KB) + lo(32KB), swizzled
#define QTABLE_BYTES 32768
#define GEMM_GRID 628          // 157 M-tiles x 4 quarters
#define ECACHE 1024            // LDS edge cache (8 KB)

typedef __attribute__((ext_vector_type(8))) short short8v;
typedef __attribute__((ext_vector_type(4))) float f32x4;
typedef __attribute__((ext_vector_type(4))) unsigned short us4;

// ---------------- zero scratch ----------------
__global__ void k_zero(int* __restrict__ degi, float* __restrict__ pooled) {
    int i = blockIdx.x * 256 + threadIdx.x;
    if (i < N_NODES) degi[i] = 0;
    if (i < N_GRAPHS * HIDDEN) pooled[i] = 0.f;
}

// ---------------- degree histogram + W-prep (fused, independent sections) ----------------
__global__ void k_degree_wprep(const int* __restrict__ dst, int* __restrict__ degi,
                               const float* __restrict__ W2, const float* __restrict__ W3,
                               const float* __restrict__ W4, const float* __restrict__ W5,
                               char* __restrict__ wt) {
    int bid = blockIdx.x;
    if (bid < 1250) {
        int e = bid * 256 + threadIdx.x;
        if (e < N_EDGES) atomicAdd(&degi[dst[e]], 1);
        return;
    }
    int wb = bid - 1250;                             // 0..1023
    int lid = wb >> 8;                               // 0..3
    int idx = (wb & 255) * 256 + threadIdx.x;
    const float* W = lid == 0 ? W2 : lid == 1 ? W3 : lid == 2 ? W4 : W5;
    int k = idx & 255, n = idx >> 8;
    float a = W[k * 256 + n];
    unsigned u = __float_as_uint(a);
    ushort hi = (ushort)(u >> 16);
    float hif = __uint_as_float(u & 0xffff0000u);
    ushort lo = (ushort)(__float_as_uint(a - hif) >> 16);
    int q = n >> 6, colQ = n & 63, slab = k >> 3, e = k & 7;
    size_t base = ((size_t)lid * 4 + q) * QPANEL_BYTES;
    size_t soff = (size_t)slab * 1024 + ((colQ * 16 + slab * 32) & 1023) + e * 2;
    *(ushort*)(wt + base + soff) = hi;
    *(ushort*)(wt + base + QTABLE_BYTES + soff) = lo;
}

// ---------------- exclusive scan of degrees -> rowptr (+rowstart, +dinv) ----------------
__global__ void k_scan(const int* __restrict__ degi, int* __restrict__ rowptr,
                       int* __restrict__ rowstart, float* __restrict__ dinv) {
    __shared__ int sums[1024];
    int t = threadIdx.x;
    int base = t * 20;
    int ld[20];
    int local = 0;
    if (t < 1000) {
#pragma unroll
        for (int i = 0; i < 20; ++i) {
            ld[i] = degi[base + i];
            local += ld[i];
            dinv[base + i] = rsqrtf((float)ld[i] + 1.0f); // +1 self-loop
        }
    }
    sums[t] = local;
    __syncthreads();
    for (int off = 1; off < 1024; off <<= 1) {
        int v = (t >= off) ? sums[t - off] : 0;
        __syncthreads();
        sums[t] += v;
        __syncthreads();
    }
    if (t < 1000) {
        int run = (t == 0) ? 0 : sums[t - 1];
#pragma unroll
        for (int i = 0; i < 20; ++i) {
            rowptr[base + i] = run;
            rowstart[base + i] = run;
            run += ld[i];
        }
    }
    if (t == 1023) rowptr[N_NODES] = sums[1023];
}

// ---------------- CSR fill ----------------
__global__ void k_fill(const int* __restrict__ src, const int* __restrict__ dst,
                       const float* __restrict__ dinv, int* __restrict__ rowstart,
                       int2* __restrict__ csr) {
    int e = blockIdx.x * blockDim.x + threadIdx.x;
    if (e >= N_EDGES) return;
    int s = src[e], d = dst[e];
    int pos = atomicAdd(&rowstart[d], 1);
    csr[pos] = make_int2(s, __float_as_int(dinv[s] * dinv[d]));
}

// ---------------- layer 1: aggregate raw 3-dim features, 4 lanes per node ----------------
__global__ void k_aggx(const float* __restrict__ x, const float* __restrict__ dinv,
                       const int* __restrict__ rowptr, const int2* __restrict__ csr,
                       float* __restrict__ z) {
    int t = blockIdx.x * blockDim.x + threadIdx.x;
    int i = t >> 2, c = t & 3;
    if (i >= N_NODES || c >= 3) return;
    float di = dinv[i];
    float a = di * di * x[i * 3 + c], bacc = 0.f;
    int k = rowptr[i], end = rowptr[i + 1];
    for (; k + 1 < end; k += 2) {
        int2 e0 = csr[k], e1 = csr[k + 1];
        a = fmaf(x[(size_t)e0.x * 3 + c], __int_as_float(e0.y), a);
        bacc = fmaf(x[(size_t)e1.x * 3 + c], __int_as_float(e1.y), bacc);
    }
    if (k < end) {
        int2 e0 = csr[k];
        a = fmaf(x[(size_t)e0.x * 3 + c], __int_as_float(e0.y), a);
    }
    z[i * 3 + c] = a + bacc;
}

// ---------------- layer 1: h1 = relu(z @ W1 + b1) -> hi/lo split ----------------
__global__ void k_h1(const float* __restrict__ z, const float* __restrict__ W1,
                     const float* __restrict__ b1,
                     ushort* __restrict__ out_hi, ushort* __restrict__ out_lo) {
    int i = blockIdx.x;
    int j = threadIdx.x;
    float z0 = z[i * 3], z1 = z[i * 3 + 1], z2 = z[i * 3 + 2];
    float v = fmaf(z0, W1[j], fmaf(z1, W1[256 + j], fmaf(z2, W1[512 + j], b1[j])));
    v = fmaxf(v, 0.0f);
    unsigned u = __float_as_uint(v);
    ushort hi = (ushort)(u >> 16);
    float hif = __uint_as_float(u & 0xffff0000u);
    ushort lo = (ushort)(__float_as_uint(v - hif) >> 16);
    out_hi[(size_t)i * HIDDEN + j] = hi;
    out_lo[(size_t)i * HIDDEN + j] = lo;
}

// ---------------- column-sliced agg (r14 form) + nontemporal gathers ----------------
// slice = bid&7 (XCD round-robin: per-XCD h-slice L2-resident). 8 lanes/node,
// 32 consecutive nodes/block, 4-deep unroll. Gathers are L1-bypass (nt): the
// 2.56MB/XCD working set has ~no L1 reuse; skip line allocation.
__global__ void k_csr_agg(const float* __restrict__ h, const float* __restrict__ dinv,
                          const int* __restrict__ rowptr, const int2* __restrict__ csr,
                          const float* __restrict__ b,
                          ushort* __restrict__ out_hi, ushort* __restrict__ out_lo) {
    __shared__ int2 ec[ECACHE];
    int bid = blockIdx.x;
    int slice = bid & 7;
    int nodeBase = (bid >> 3) * 32;
    int begB = rowptr[nodeBase];
    int total = rowptr[nodeBase + 32] - begB;
    bool cached = (total <= ECACHE);
    if (cached) {
        for (int i = threadIdx.x; i < total; i += 256) ec[i] = csr[begB + i];
        __syncthreads();
    }
    int node = nodeBase + (threadIdx.x >> 3);
    int cl = threadIdx.x & 7;
    int scol = slice * 32 + cl * 4;
    int beg = rowptr[node] - begB, end = rowptr[node + 1] - begB;
    const int2* ep = cached ? ec : (csr + begB);
    f32x4 A0 = {0,0,0,0}, A1 = {0,0,0,0}, A2 = {0,0,0,0}, A3 = {0,0,0,0};
    int k = beg;
    for (; k + 3 < end; k += 4) {
        int2 e0 = ep[k], e1 = ep[k + 1], e2 = ep[k + 2], e3 = ep[k + 3];
        float w0 = __int_as_float(e0.y), w1 = __int_as_float(e1.y);
        float w2 = __int_as_float(e2.y), w3 = __int_as_float(e3.y);
        f32x4 v0 = __builtin_nontemporal_load(
            reinterpret_cast<const f32x4*>(h + (size_t)e0.x * HIDDEN + scol));
        f32x4 v1 = __builtin_nontemporal_load(
            reinterpret_cast<const f32x4*>(h + (size_t)e1.x * HIDDEN + scol));
        f32x4 v2 = __builtin_nontemporal_load(
            reinterpret_cast<const f32x4*>(h + (size_t)e2.x * HIDDEN + scol));
        f32x4 v3 = __builtin_nontemporal_load(
            reinterpret_cast<const f32x4*>(h + (size_t)e3.x * HIDDEN + scol));
#pragma unroll
        for (int j = 0; j < 4; ++j) {
            A0[j] = fmaf(v0[j], w0, A0[j]);
            A1[j] = fmaf(v1[j], w1, A1[j]);
            A2[j] = fmaf(v2[j], w2, A2[j]);
            A3[j] = fmaf(v3[j], w3, A3[j]);
        }
    }
    if (k + 1 < end) {
        int2 e0 = ep[k], e1 = ep[k + 1];
        float w0 = __int_as_float(e0.y), w1 = __int_as_float(e1.y);
        f32x4 v0 = __builtin_nontemporal_load(
            reinterpret_cast<const f32x4*>(h + (size_t)e0.x * HIDDEN + scol));
        f32x4 v1 = __builtin_nontemporal_load(
            reinterpret_cast<const f32x4*>(h + (size_t)e1.x * HIDDEN + scol));
#pragma unroll
        for (int j = 0; j < 4; ++j) {
            A0[j] = fmaf(v0[j], w0, A0[j]);
            A1[j] = fmaf(v1[j], w1, A1[j]);
        }
        k += 2;
    }
    if (k < end) {
        int2 e0 = ep[k];
        float w0 = __int_as_float(e0.y);
        f32x4 v0 = __builtin_nontemporal_load(
            reinterpret_cast<const f32x4*>(h + (size_t)e0.x * HIDDEN + scol));
#pragma unroll
        for (int j = 0; j < 4; ++j) A0[j] = fmaf(v0[j], w0, A0[j]);
    }
    float di = dinv[node];
    float ws = di * di;
    f32x4 bv = *reinterpret_cast<const f32x4*>(b + scol);
    f32x4 hv = *reinterpret_cast<const f32x4*>(h + (size_t)node * HIDDEN + scol);
    us4 hvv, lvv;
#pragma unroll
    for (int j = 0; j < 4; ++j) {
        float rv = fmaxf(fmaf(hv[j], ws, bv[j] + (A0[j] + A1[j]) + (A2[j] + A3[j])), 0.f);
        unsigned u = __float_as_uint(rv);
        hvv[j] = (ushort)(u >> 16);
        float hif = __uint_as_float(u & 0xffff0000u);
        lvv[j] = (ushort)(__float_as_uint(rv - hif) >> 16);
    }
    *reinterpret_cast<us4*>(out_hi + (size_t)node * HIDDEN + scol) = hvv;
    *reinterpret_cast<us4*>(out_lo + (size_t)node * HIDDEN + scol) = lvv;
}

// ---------------- MFMA split-bf16 GEMM, XCD-grouped, 2-stage A prefetch ----------------
__global__ __launch_bounds__(512) void k_gemm_mfma(const ushort* __restrict__ a_hi,
                                                   const ushort* __restrict__ a_lo,
                                                   const char* __restrict__ wpanels,
                                                   float* __restrict__ out) {
    __shared__ char smem[QPANEL_BYTES];
    int d = blockIdx.x;
    int xcd = d & 7, idx = d >> 3;
    const int q0 = GEMM_GRID / 8, r = GEMM_GRID % 8;   // 78, 4
    int base = xcd * q0 + (xcd < r ? xcd : r);
    int logical = base + idx;
    int mtile = logical >> 2, q = logical & 3;

    const char* gsrc = wpanels + (size_t)q * QPANEL_BYTES;
    int tid = threadIdx.x;
#pragma unroll
    for (int it = 0; it < 8; ++it) {
        int o = it * 8192 + tid * 16;
        *reinterpret_cast<float4*>(smem + o) = *reinterpret_cast<const float4*>(gsrc + o);
    }
    __syncthreads();

    int w = tid >> 6, l = tid & 63;
    int lr = l & 15, kg = l >> 4;
    int wm = w >> 1, wn = w & 1;          // 4M x 2N
    int row0 = mtile * 128 + wm * 32;
    int colQ0 = wn * 32;

    const ushort* aph = a_hi + (size_t)(row0 + lr) * HIDDEN + kg * 8;
    const ushort* apl = a_lo + (size_t)(row0 + lr) * HIDDEN + kg * 8;

    // prefetch t=0
    short8v ah0 = *reinterpret_cast<const short8v*>(aph);
    short8v ah1 = *reinterpret_cast<const short8v*>(aph + 16 * HIDDEN);
    short8v al0 = *reinterpret_cast<const short8v*>(apl);
    short8v al1 = *reinterpret_cast<const short8v*>(apl + 16 * HIDDEN);

    f32x4 acc[2][2] = {};
#pragma unroll
    for (int t = 0; t < 8; ++t) {
        short8v cah0 = ah0, cah1 = ah1, cal0 = al0, cal1 = al1;
        if (t < 7) {
            int kb = (t + 1) * 32;
            ah0 = *reinterpret_cast<const short8v*>(aph + kb);
            ah1 = *reinterpret_cast<const short8v*>(aph + 16 * HIDDEN + kb);
            al0 = *reinterpret_cast<const short8v*>(apl + kb);
            al1 = *reinterpret_cast<const short8v*>(apl + 16 * HIDDEN + kb);
        }
        int slab = t * 4 + kg;
        int sbase = slab * 1024;
        int rot = slab * 32;
        int off0 = sbase + (((colQ0 + lr) * 16 + rot) & 1023);
        int off1 = sbase + (((colQ0 + 16 + lr) * 16 + rot) & 1023);
        short8v bh0 = *reinterpret_cast<const short8v*>(smem + off0);
        short8v bh1 = *reinterpret_cast<const short8v*>(smem + off1);
        short8v bl0 = *reinterpret_cast<const short8v*>(smem + QTABLE_BYTES + off0);
        short8v bl1 = *reinterpret_cast<const short8v*>(smem + QTABLE_BYTES + off1);
        acc[0][0] = __builtin_amdgcn_mfma_f32_16x16x32_bf16(cah0, bh0, acc[0][0], 0, 0, 0);
        acc[1][0] = __builtin_amdgcn_mfma_f32_16x16x32_bf16(cah1, bh0, acc[1][0], 0, 0, 0);
        acc[0][1] = __builtin_amdgcn_mfma_f32_16x16x32_bf16(cah0, bh1, acc[0][1], 0, 0, 0);
        acc[1][1] = __builtin_amdgcn_mfma_f32_16x16x32_bf16(cah1, bh1, acc[1][1], 0, 0, 0);
        acc[0][0] = __builtin_amdgcn_mfma_f32_16x16x32_bf16(cal0, bh0, acc[0][0], 0, 0, 0);
        acc[1][0] = __builtin_amdgcn_mfma_f32_16x16x32_bf16(cal1, bh0, acc[1][0], 0, 0, 0);
        acc[0][1] = __builtin_amdgcn_mfma_f32_16x16x32_bf16(cal0, bh1, acc[0][1], 0, 0, 0);
        acc[1][1] = __builtin_amdgcn_mfma_f32_16x16x32_bf16(cal1, bh1, acc[1][1], 0, 0, 0);
        acc[0][0] = __builtin_amdgcn_mfma_f32_16x16x32_bf16(cah0, bl0, acc[0][0], 0, 0, 0);
        acc[1][0] = __builtin_amdgcn_mfma_f32_16x16x32_bf16(cah1, bl0, acc[1][0], 0, 0, 0);
        acc[0][1] = __builtin_amdgcn_mfma_f32_16x16x32_bf16(cah0, bl1, acc[0][1], 0, 0, 0);
        acc[1][1] = __builtin_amdgcn_mfma_f32_16x16x32_bf16(cah1, bl1, acc[1][1], 0, 0, 0);
    }
    // C/D layout: col = lane&15, row = (lane>>4)*4 + reg   [m89-verified]
    int gcol = q * 64 + colQ0 + lr;
#pragma unroll
    for (int rf = 0; rf < 2; ++rf) {
        float* o0 = out + (size_t)(row0 + rf * 16 + kg * 4) * HIDDEN + gcol;
#pragma unroll
        for (int rr = 0; rr < 4; ++rr)
#pragma unroll
            for (int cf = 0; cf < 2; ++cf)
                o0[(size_t)rr * HIDDEN + cf * 16] = acc[rf][cf][rr];
    }
}

// ---------------- pooling from hi/lo (already relu'd) ----------------
__global__ void k_pool(const ushort* __restrict__ hi, const ushort* __restrict__ lo,
                       const int* __restrict__ batch, float* __restrict__ pooled) {
    int base = blockIdx.x * 32;
    int j = threadIdx.x;
    float acc = 0.0f;
    int cur = batch[base];
    for (int r = 0; r < 32; ++r) {
        int i = base + r;
        int bg = batch[i];
        if (bg != cur) {
            atomicAdd(&pooled[cur * HIDDEN + j], acc);
            acc = 0.0f;
            cur = bg;
        }
        size_t off = (size_t)i * HIDDEN + j;
        float v = __uint_as_float((unsigned)hi[off] << 16) +
                  __uint_as_float((unsigned)lo[off] << 16);
        acc += v;
    }
    atomicAdd(&pooled[cur * HIDDEN + j], acc);
}

// ---------------- final linear ----------------
__global__ void k_final(const float* __restrict__ pooled, const float* __restrict__ Wlin,
                        const float* __restrict__ blin, float* __restrict__ out) {
    int t = threadIdx.x; // 0..127
    int g = t >> 1, o = t & 1;
    float s = blin[o];
    for (int k = 0; k < HIDDEN; ++k) s += pooled[g * HIDDEN + k] * Wlin[k * OUT_DIM + o];
    out[g * OUT_DIM + o] = s;
}

extern "C" void kernel_launch(void* const* d_in, const int* in_sizes, int n_in,
                              void* d_out, int out_size, void* d_ws, size_t ws_size,
                              hipStream_t stream) {
    const float* x     = (const float*)d_in[0];
    const int*   esrc  = (const int*)d_in[1];
    const int*   edst  = esrc + N_EDGES;
    const int*   batch = (const int*)d_in[2];
    const float* W1 = (const float*)d_in[3];
    const float* b1 = (const float*)d_in[4];
    const float* W2 = (const float*)d_in[5];
    const float* b2 = (const float*)d_in[6];
    const float* W3 = (const float*)d_in[7];
    const float* b3 = (const float*)d_in[8];
    const float* W4 = (const float*)d_in[9];
    const float* b4 = (const float*)d_in[10];
    const float* W5 = (const float*)d_in[11];
    const float* b5 = (const float*)d_in[12];
    const float* Wlin = (const float*)d_in[13];
    const float* blin = (const float*)d_in[14];
    float* out = (float*)d_out;

    char* ws = (char*)d_ws;
    size_t off = 0;
    auto alloc = [&](size_t bytes) { size_t o = off; off += (bytes + 255) & ~size_t(255); return (void*)(ws + o); };

    int*    degi     = (int*)alloc(N_NODES * 4);
    float*  dinv     = (float*)alloc(N_NODES * 4);
    int*    rowptr   = (int*)alloc((N_NODES + 1) * 4);
    int*    rowstart = (int*)alloc(N_NODES * 4);
    int2*   csr      = (int2*)alloc((size_t)N_EDGES * 8);
    float*  hA       = (float*)alloc((size_t)N_PAD * HIDDEN * 4);
    ushort* hb_hi    = (ushort*)alloc((size_t)N_PAD * HIDDEN * 2);
    ushort* hb_lo    = (ushort*)alloc((size_t)N_PAD * HIDDEN * 2);
    float*  pooled   = (float*)alloc(N_GRAPHS * HIDDEN * 4);
    char*   wt       = (char*)alloc((size_t)4 * 4 * QPANEL_BYTES);
    float*  z        = (float*)alloc((size_t)N_NODES * 3 * 4);

    k_zero<<<(N_NODES + 255) / 256, 256, 0, stream>>>(degi, pooled);
    k_degree_wprep<<<1250 + 1024, 256, 0, stream>>>(edst, degi, W2, W3, W4, W5, wt);
    k_scan<<<1, 1024, 0, stream>>>(degi, rowptr, rowstart, dinv);
    k_fill<<<(N_EDGES + 255) / 256, 256, 0, stream>>>(esrc, edst, dinv, rowstart, csr);

    const float* bs[5] = {b1, b2, b3, b4, b5};

    // layer 1 (reassociated): z = A*x, h1 = relu(z @ W1 + b1)
    k_aggx<<<(N_NODES * 4 + 255) / 256, 256, 0, stream>>>(x, dinv, rowptr, csr, z);
    k_h1<<<N_NODES, HIDDEN, 0, stream>>>(z, W1, b1, hb_hi, hb_lo);

    // layers 2..5
    for (int l = 1; l < 5; ++l) {
        k_gemm_mfma<<<GEMM_GRID, 512, 0, stream>>>(
            hb_hi, hb_lo, wt + (size_t)(l - 1) * 4 * QPANEL_BYTES, hA);
        k_csr_agg<<<(N_NODES / 32) * 8, 256, 0, stream>>>(
            hA, dinv, rowptr, csr, bs[l], hb_hi, hb_lo);
    }

    k_pool<<<N_NODES / 32, HIDDEN, 0, stream>>>(hb_hi, hb_lo, batch, pooled);
    k_final<<<1, 128, 0, stream>>>(pooled, Wlin, blin, out);
}

// Round 20
// 341.817 us; speedup vs baseline: 1.2770x; 1.2770x over previous
//
#include <hip/hip_runtime.h>

#define N_NODES 20000
#define N_PAD 20096            // 157 * 128
#define N_EDGES 320000
#define HIDDEN 256
#define N_GRAPHS 64
#define OUT_DIM 2

#define QPANEL_BYTES 65536     // one col-quarter (64 cols): hi(32KB) + lo(32KB), swizzled
#define QTABLE_BYTES 32768
#define GEMM_GRID 628          // 157 M-tiles x 4 quarters
#define ECACHE 1536            // LDS edge cache (12 KB)

typedef __attribute__((ext_vector_type(8))) short short8v;
typedef __attribute__((ext_vector_type(4))) float f32x4;
typedef __attribute__((ext_vector_type(4))) unsigned short us4;

// ---------------- zero scratch ----------------
__global__ void k_zero(int* __restrict__ degi, float* __restrict__ pooled) {
    int i = blockIdx.x * 256 + threadIdx.x;
    if (i < N_NODES) degi[i] = 0;
    if (i < N_GRAPHS * HIDDEN) pooled[i] = 0.f;
}

// ---------------- degree histogram + W-prep (fused, independent sections) ----------------
__global__ void k_degree_wprep(const int* __restrict__ dst, int* __restrict__ degi,
                               const float* __restrict__ W2, const float* __restrict__ W3,
                               const float* __restrict__ W4, const float* __restrict__ W5,
                               char* __restrict__ wt) {
    int bid = blockIdx.x;
    if (bid < 1250) {
        int e = bid * 256 + threadIdx.x;
        if (e < N_EDGES) atomicAdd(&degi[dst[e]], 1);
        return;
    }
    int wb = bid - 1250;                             // 0..1023
    int lid = wb >> 8;                               // 0..3
    int idx = (wb & 255) * 256 + threadIdx.x;
    const float* W = lid == 0 ? W2 : lid == 1 ? W3 : lid == 2 ? W4 : W5;
    int k = idx & 255, n = idx >> 8;
    float a = W[k * 256 + n];
    unsigned u = __float_as_uint(a);
    ushort hi = (ushort)(u >> 16);
    float hif = __uint_as_float(u & 0xffff0000u);
    ushort lo = (ushort)(__float_as_uint(a - hif) >> 16);
    int q = n >> 6, colQ = n & 63, slab = k >> 3, e = k & 7;
    size_t base = ((size_t)lid * 4 + q) * QPANEL_BYTES;
    size_t soff = (size_t)slab * 1024 + ((colQ * 16 + slab * 32) & 1023) + e * 2;
    *(ushort*)(wt + base + soff) = hi;
    *(ushort*)(wt + base + QTABLE_BYTES + soff) = lo;
}

// ---------------- exclusive scan of degrees -> rowptr (+rowstart, +dinv) ----------------
__global__ void k_scan(const int* __restrict__ degi, int* __restrict__ rowptr,
                       int* __restrict__ rowstart, float* __restrict__ dinv) {
    __shared__ int sums[1024];
    int t = threadIdx.x;
    int base = t * 20;
    int ld[20];
    int local = 0;
    if (t < 1000) {
#pragma unroll
        for (int i = 0; i < 20; ++i) {
            ld[i] = degi[base + i];
            local += ld[i];
            dinv[base + i] = rsqrtf((float)ld[i] + 1.0f); // +1 self-loop
        }
    }
    sums[t] = local;
    __syncthreads();
    for (int off = 1; off < 1024; off <<= 1) {
        int v = (t >= off) ? sums[t - off] : 0;
        __syncthreads();
        sums[t] += v;
        __syncthreads();
    }
    if (t < 1000) {
        int run = (t == 0) ? 0 : sums[t - 1];
#pragma unroll
        for (int i = 0; i < 20; ++i) {
            rowptr[base + i] = run;
            rowstart[base + i] = run;
            run += ld[i];
        }
    }
    if (t == 1023) rowptr[N_NODES] = sums[1023];
}

// ---------------- CSR fill ----------------
__global__ void k_fill(const int* __restrict__ src, const int* __restrict__ dst,
                       const float* __restrict__ dinv, int* __restrict__ rowstart,
                       int2* __restrict__ csr) {
    int e = blockIdx.x * blockDim.x + threadIdx.x;
    if (e >= N_EDGES) return;
    int s = src[e], d = dst[e];
    int pos = atomicAdd(&rowstart[d], 1);
    csr[pos] = make_int2(s, __float_as_int(dinv[s] * dinv[d]));
}

// ---------------- layer 1: aggregate raw 3-dim features, 4 lanes per node ----------------
__global__ void k_aggx(const float* __restrict__ x, const float* __restrict__ dinv,
                       const int* __restrict__ rowptr, const int2* __restrict__ csr,
                       float* __restrict__ z) {
    int t = blockIdx.x * blockDim.x + threadIdx.x;
    int i = t >> 2, c = t & 3;
    if (i >= N_NODES || c >= 3) return;
    float di = dinv[i];
    float a = di * di * x[i * 3 + c], bacc = 0.f;
    int k = rowptr[i], end = rowptr[i + 1];
    for (; k + 1 < end; k += 2) {
        int2 e0 = csr[k], e1 = csr[k + 1];
        a = fmaf(x[(size_t)e0.x * 3 + c], __int_as_float(e0.y), a);
        bacc = fmaf(x[(size_t)e1.x * 3 + c], __int_as_float(e1.y), bacc);
    }
    if (k < end) {
        int2 e0 = csr[k];
        a = fmaf(x[(size_t)e0.x * 3 + c], __int_as_float(e0.y), a);
    }
    z[i * 3 + c] = a + bacc;
}

// ---------------- layer 1: h1 = relu(z @ W1 + b1) -> hi/lo split ----------------
__global__ void k_h1(const float* __restrict__ z, const float* __restrict__ W1,
                     const float* __restrict__ b1,
                     ushort* __restrict__ out_hi, ushort* __restrict__ out_lo) {
    int i = blockIdx.x;
    int j = threadIdx.x;
    float z0 = z[i * 3], z1 = z[i * 3 + 1], z2 = z[i * 3 + 2];
    float v = fmaf(z0, W1[j], fmaf(z1, W1[256 + j], fmaf(z2, W1[512 + j], b1[j])));
    v = fmaxf(v, 0.0f);
    unsigned u = __float_as_uint(v);
    ushort hi = (ushort)(u >> 16);
    float hif = __uint_as_float(u & 0xffff0000u);
    ushort lo = (ushort)(__float_as_uint(v - hif) >> 16);
    out_hi[(size_t)i * HIDDEN + j] = hi;
    out_lo[(size_t)i * HIDDEN + j] = lo;
}

// ---------------- column-sliced agg with LDS edge cache (r14 best form) ----------------
// slice = bid&7 (XCD round-robin: per-XCD h-slice L2-resident). Block's 32 consecutive
// nodes have one CONTIGUOUS csr span -> bulk-load into LDS (coalesced). 8 lanes/node,
// 4-deep unrolled gather MLP; plain loads (L2-allocating — nt regressed 2x, r19).
__global__ void k_csr_agg(const float* __restrict__ h, const float* __restrict__ dinv,
                          const int* __restrict__ rowptr, const int2* __restrict__ csr,
                          const float* __restrict__ b,
                          ushort* __restrict__ out_hi, ushort* __restrict__ out_lo) {
    __shared__ int2 ec[ECACHE];
    int bid = blockIdx.x;
    int slice = bid & 7;
    int nodeBase = (bid >> 3) * 32;
    int begB = rowptr[nodeBase];
    int total = rowptr[nodeBase + 32] - begB;
    bool cached = (total <= ECACHE);
    if (cached) {
        for (int i = threadIdx.x; i < total; i += 256) ec[i] = csr[begB + i];
        __syncthreads();
    }
    int node = nodeBase + (threadIdx.x >> 3);
    int cl = threadIdx.x & 7;
    int scol = slice * 32 + cl * 4;
    int beg = rowptr[node] - begB, end = rowptr[node + 1] - begB;
    const int2* ep = cached ? ec : (csr + begB);
    float4 A0 = {0,0,0,0}, A1 = {0,0,0,0}, A2 = {0,0,0,0}, A3 = {0,0,0,0};
    int k = beg;
    for (; k + 3 < end; k += 4) {
        int2 e0 = ep[k], e1 = ep[k + 1], e2 = ep[k + 2], e3 = ep[k + 3];
        float w0 = __int_as_float(e0.y), w1 = __int_as_float(e1.y);
        float w2 = __int_as_float(e2.y), w3 = __int_as_float(e3.y);
        float4 v0 = *reinterpret_cast<const float4*>(h + (size_t)e0.x * HIDDEN + scol);
        float4 v1 = *reinterpret_cast<const float4*>(h + (size_t)e1.x * HIDDEN + scol);
        float4 v2 = *reinterpret_cast<const float4*>(h + (size_t)e2.x * HIDDEN + scol);
        float4 v3 = *reinterpret_cast<const float4*>(h + (size_t)e3.x * HIDDEN + scol);
        A0.x = fmaf(v0.x, w0, A0.x);  A1.x = fmaf(v1.x, w1, A1.x);
        A0.y = fmaf(v0.y, w0, A0.y);  A1.y = fmaf(v1.y, w1, A1.y);
        A0.z = fmaf(v0.z, w0, A0.z);  A1.z = fmaf(v1.z, w1, A1.z);
        A0.w = fmaf(v0.w, w0, A0.w);  A1.w = fmaf(v1.w, w1, A1.w);
        A2.x = fmaf(v2.x, w2, A2.x);  A3.x = fmaf(v3.x, w3, A3.x);
        A2.y = fmaf(v2.y, w2, A2.y);  A3.y = fmaf(v3.y, w3, A3.y);
        A2.z = fmaf(v2.z, w2, A2.z);  A3.z = fmaf(v3.z, w3, A3.z);
        A2.w = fmaf(v2.w, w2, A2.w);  A3.w = fmaf(v3.w, w3, A3.w);
    }
    if (k + 1 < end) {
        int2 e0 = ep[k], e1 = ep[k + 1];
        float w0 = __int_as_float(e0.y), w1 = __int_as_float(e1.y);
        float4 v0 = *reinterpret_cast<const float4*>(h + (size_t)e0.x * HIDDEN + scol);
        float4 v1 = *reinterpret_cast<const float4*>(h + (size_t)e1.x * HIDDEN + scol);
        A0.x = fmaf(v0.x, w0, A0.x);  A1.x = fmaf(v1.x, w1, A1.x);
        A0.y = fmaf(v0.y, w0, A0.y);  A1.y = fmaf(v1.y, w1, A1.y);
        A0.z = fmaf(v0.z, w0, A0.z);  A1.z = fmaf(v1.z, w1, A1.z);
        A0.w = fmaf(v0.w, w0, A0.w);  A1.w = fmaf(v1.w, w1, A1.w);
        k += 2;
    }
    if (k < end) {
        int2 e0 = ep[k];
        float w0 = __int_as_float(e0.y);
        float4 v0 = *reinterpret_cast<const float4*>(h + (size_t)e0.x * HIDDEN + scol);
        A0.x = fmaf(v0.x, w0, A0.x);
        A0.y = fmaf(v0.y, w0, A0.y);
        A0.z = fmaf(v0.z, w0, A0.z);
        A0.w = fmaf(v0.w, w0, A0.w);
    }
    float di = dinv[node];
    float ws = di * di;
    float4 bv = *reinterpret_cast<const float4*>(b + scol);
    float4 hv = *reinterpret_cast<const float4*>(h + (size_t)node * HIDDEN + scol);
    float rv[4];
    rv[0] = fmaxf(fmaf(hv.x, ws, bv.x + (A0.x + A1.x) + (A2.x + A3.x)), 0.f);
    rv[1] = fmaxf(fmaf(hv.y, ws, bv.y + (A0.y + A1.y) + (A2.y + A3.y)), 0.f);
    rv[2] = fmaxf(fmaf(hv.z, ws, bv.z + (A0.z + A1.z) + (A2.z + A3.z)), 0.f);
    rv[3] = fmaxf(fmaf(hv.w, ws, bv.w + (A0.w + A1.w) + (A2.w + A3.w)), 0.f);
    us4 hvv, lvv;
#pragma unroll
    for (int j = 0; j < 4; ++j) {
        unsigned u = __float_as_uint(rv[j]);
        hvv[j] = (ushort)(u >> 16);
        float hif = __uint_as_float(u & 0xffff0000u);
        lvv[j] = (ushort)(__float_as_uint(rv[j] - hif) >> 16);
    }
    *reinterpret_cast<us4*>(out_hi + (size_t)node * HIDDEN + scol) = hvv;
    *reinterpret_cast<us4*>(out_lo + (size_t)node * HIDDEN + scol) = lvv;
}

// ---------------- MFMA split-bf16 GEMM, XCD-grouped, 2-stage A prefetch ----------------
__global__ __launch_bounds__(512) void k_gemm_mfma(const ushort* __restrict__ a_hi,
                                                   const ushort* __restrict__ a_lo,
                                                   const char* __restrict__ wpanels,
                                                   float* __restrict__ out) {
    __shared__ char smem[QPANEL_BYTES];
    int d = blockIdx.x;
    int xcd = d & 7, idx = d >> 3;
    const int q0 = GEMM_GRID / 8, r = GEMM_GRID % 8;   // 78, 4
    int base = xcd * q0 + (xcd < r ? xcd : r);
    int logical = base + idx;
    int mtile = logical >> 2, q = logical & 3;

    const char* gsrc = wpanels + (size_t)q * QPANEL_BYTES;
    int tid = threadIdx.x;
#pragma unroll
    for (int it = 0; it < 8; ++it) {
        int o = it * 8192 + tid * 16;
        *reinterpret_cast<float4*>(smem + o) = *reinterpret_cast<const float4*>(gsrc + o);
    }
    __syncthreads();

    int w = tid >> 6, l = tid & 63;
    int lr = l & 15, kg = l >> 4;
    int wm = w >> 1, wn = w & 1;          // 4M x 2N
    int row0 = mtile * 128 + wm * 32;
    int colQ0 = wn * 32;

    const ushort* aph = a_hi + (size_t)(row0 + lr) * HIDDEN + kg * 8;
    const ushort* apl = a_lo + (size_t)(row0 + lr) * HIDDEN + kg * 8;

    // prefetch t=0
    short8v ah0 = *reinterpret_cast<const short8v*>(aph);
    short8v ah1 = *reinterpret_cast<const short8v*>(aph + 16 * HIDDEN);
    short8v al0 = *reinterpret_cast<const short8v*>(apl);
    short8v al1 = *reinterpret_cast<const short8v*>(apl + 16 * HIDDEN);

    f32x4 acc[2][2] = {};
#pragma unroll
    for (int t = 0; t < 8; ++t) {
        short8v cah0 = ah0, cah1 = ah1, cal0 = al0, cal1 = al1;
        if (t < 7) {
            int kb = (t + 1) * 32;
            ah0 = *reinterpret_cast<const short8v*>(aph + kb);
            ah1 = *reinterpret_cast<const short8v*>(aph + 16 * HIDDEN + kb);
            al0 = *reinterpret_cast<const short8v*>(apl + kb);
            al1 = *reinterpret_cast<const short8v*>(apl + 16 * HIDDEN + kb);
        }
        int slab = t * 4 + kg;
        int sbase = slab * 1024;
        int rot = slab * 32;
        int off0 = sbase + (((colQ0 + lr) * 16 + rot) & 1023);
        int off1 = sbase + (((colQ0 + 16 + lr) * 16 + rot) & 1023);
        short8v bh0 = *reinterpret_cast<const short8v*>(smem + off0);
        short8v bh1 = *reinterpret_cast<const short8v*>(smem + off1);
        short8v bl0 = *reinterpret_cast<const short8v*>(smem + QTABLE_BYTES + off0);
        short8v bl1 = *reinterpret_cast<const short8v*>(smem + QTABLE_BYTES + off1);
        acc[0][0] = __builtin_amdgcn_mfma_f32_16x16x32_bf16(cah0, bh0, acc[0][0], 0, 0, 0);
        acc[1][0] = __builtin_amdgcn_mfma_f32_16x16x32_bf16(cah1, bh0, acc[1][0], 0, 0, 0);
        acc[0][1] = __builtin_amdgcn_mfma_f32_16x16x32_bf16(cah0, bh1, acc[0][1], 0, 0, 0);
        acc[1][1] = __builtin_amdgcn_mfma_f32_16x16x32_bf16(cah1, bh1, acc[1][1], 0, 0, 0);
        acc[0][0] = __builtin_amdgcn_mfma_f32_16x16x32_bf16(cal0, bh0, acc[0][0], 0, 0, 0);
        acc[1][0] = __builtin_amdgcn_mfma_f32_16x16x32_bf16(cal1, bh0, acc[1][0], 0, 0, 0);
        acc[0][1] = __builtin_amdgcn_mfma_f32_16x16x32_bf16(cal0, bh1, acc[0][1], 0, 0, 0);
        acc[1][1] = __builtin_amdgcn_mfma_f32_16x16x32_bf16(cal1, bh1, acc[1][1], 0, 0, 0);
        acc[0][0] = __builtin_amdgcn_mfma_f32_16x16x32_bf16(cah0, bl0, acc[0][0], 0, 0, 0);
        acc[1][0] = __builtin_amdgcn_mfma_f32_16x16x32_bf16(cah1, bl0, acc[1][0], 0, 0, 0);
        acc[0][1] = __builtin_amdgcn_mfma_f32_16x16x32_bf16(cah0, bl1, acc[0][1], 0, 0, 0);
        acc[1][1] = __builtin_amdgcn_mfma_f32_16x16x32_bf16(cah1, bl1, acc[1][1], 0, 0, 0);
    }
    // C/D layout: col = lane&15, row = (lane>>4)*4 + reg   [m89-verified]
    int gcol = q * 64 + colQ0 + lr;
#pragma unroll
    for (int rf = 0; rf < 2; ++rf) {
        float* o0 = out + (size_t)(row0 + rf * 16 + kg * 4) * HIDDEN + gcol;
#pragma unroll
        for (int rr = 0; rr < 4; ++rr)
#pragma unroll
            for (int cf = 0; cf < 2; ++cf)
                o0[(size_t)rr * HIDDEN + cf * 16] = acc[rf][cf][rr];
    }
}

// ---------------- pooling from hi/lo (already relu'd) ----------------
__global__ void k_pool(const ushort* __restrict__ hi, const ushort* __restrict__ lo,
                       const int* __restrict__ batch, float* __restrict__ pooled) {
    int base = blockIdx.x * 32;
    int j = threadIdx.x;
    float acc = 0.0f;
    int cur = batch[base];
    for (int r = 0; r < 32; ++r) {
        int i = base + r;
        int bg = batch[i];
        if (bg != cur) {
            atomicAdd(&pooled[cur * HIDDEN + j], acc);
            acc = 0.0f;
            cur = bg;
        }
        size_t off = (size_t)i * HIDDEN + j;
        float v = __uint_as_float((unsigned)hi[off] << 16) +
                  __uint_as_float((unsigned)lo[off] << 16);
        acc += v;
    }
    atomicAdd(&pooled[cur * HIDDEN + j], acc);
}

// ---------------- final linear ----------------
__global__ void k_final(const float* __restrict__ pooled, const float* __restrict__ Wlin,
                        const float* __restrict__ blin, float* __restrict__ out) {
    int t = threadIdx.x; // 0..127
    int g = t >> 1, o = t & 1;
    float s = blin[o];
    for (int k = 0; k < HIDDEN; ++k) s += pooled[g * HIDDEN + k] * Wlin[k * OUT_DIM + o];
    out[g * OUT_DIM + o] = s;
}

extern "C" void kernel_launch(void* const* d_in, const int* in_sizes, int n_in,
                              void* d_out, int out_size, void* d_ws, size_t ws_size,
                              hipStream_t stream) {
    const float* x     = (const float*)d_in[0];
    const int*   esrc  = (const int*)d_in[1];
    const int*   edst  = esrc + N_EDGES;
    const int*   batch = (const int*)d_in[2];
    const float* W1 = (const float*)d_in[3];
    const float* b1 = (const float*)d_in[4];
    const float* W2 = (const float*)d_in[5];
    const float* b2 = (const float*)d_in[6];
    const float* W3 = (const float*)d_in[7];
    const float* b3 = (const float*)d_in[8];
    const float* W4 = (const float*)d_in[9];
    const float* b4 = (const float*)d_in[10];
    const float* W5 = (const float*)d_in[11];
    const float* b5 = (const float*)d_in[12];
    const float* Wlin = (const float*)d_in[13];
    const float* blin = (const float*)d_in[14];
    float* out = (float*)d_out;

    char* ws = (char*)d_ws;
    size_t off = 0;
    auto alloc = [&](size_t bytes) { size_t o = off; off += (bytes + 255) & ~size_t(255); return (void*)(ws + o); };

    int*    degi     = (int*)alloc(N_NODES * 4);
    float*  dinv     = (float*)alloc(N_NODES * 4);
    int*    rowptr   = (int*)alloc((N_NODES + 1) * 4);
    int*    rowstart = (int*)alloc(N_NODES * 4);
    int2*   csr      = (int2*)alloc((size_t)N_EDGES * 8);
    float*  hA       = (float*)alloc((size_t)N_PAD * HIDDEN * 4);
    ushort* hb_hi    = (ushort*)alloc((size_t)N_PAD * HIDDEN * 2);
    ushort* hb_lo    = (ushort*)alloc((size_t)N_PAD * HIDDEN * 2);
    float*  pooled   = (float*)alloc(N_GRAPHS * HIDDEN * 4);
    char*   wt       = (char*)alloc((size_t)4 * 4 * QPANEL_BYTES);
    float*  z        = (float*)alloc((size_t)N_NODES * 3 * 4);

    k_zero<<<(N_NODES + 255) / 256, 256, 0, stream>>>(degi, pooled);
    k_degree_wprep<<<1250 + 1024, 256, 0, stream>>>(edst, degi, W2, W3, W4, W5, wt);
    k_scan<<<1, 1024, 0, stream>>>(degi, rowptr, rowstart, dinv);
    k_fill<<<(N_EDGES + 255) / 256, 256, 0, stream>>>(esrc, edst, dinv, rowstart, csr);

    const float* bs[5] = {b1, b2, b3, b4, b5};

    // layer 1 (reassociated): z = A*x, h1 = relu(z @ W1 + b1)
    k_aggx<<<(N_NODES * 4 + 255) / 256, 256, 0, stream>>>(x, dinv, rowptr, csr, z);
    k_h1<<<N_NODES, HIDDEN, 0, stream>>>(z, W1, b1, hb_hi, hb_lo);

    // layers 2..5
    for (int l = 1; l < 5; ++l) {
        k_gemm_mfma<<<GEMM_GRID, 512, 0, stream>>>(
            hb_hi, hb_lo, wt + (size_t)(l - 1) * 4 * QPANEL_BYTES, hA);
        k_csr_agg<<<(N_NODES / 32) * 8, 256, 0, stream>>>(
            hA, dinv, rowptr, csr, bs[l], hb_hi, hb_lo);
    }

    k_pool<<<N_NODES / 32, HIDDEN, 0, stream>>>(hb_hi, hb_lo, batch, pooled);
    k_final<<<1, 128, 0, stream>>>(pooled, Wlin, blin, out);
}